// Round 9
// baseline (182.205 us; speedup 1.0000x reference)
//
#include <hip/hip_runtime.h>

// GCN layer: segment_sum(x@W^T)[dst] == segment_sum(x)[dst] @ W^T (linearity).
// Round-22: 2 dispatches.
//   prep_sort   : (r20, kept) block-local LDS counting sort; coalesced
//                 binned write; column-major off table.
//   sort_gather : SUPER-BUCKET blocks — 4 buckets (256 nodes) per block,
//                 512 thr. Island reads merge: buckets 4g..4g+3 are
//                 CONTIGUOUS within each prep block region, so one ~96B
//                 span replaces four ~24B islands (sector waste 10KB ->
//                 2KB per bucket, ~-20MB FETCH). Bucket bits recovered
//                 from off-table splits: raw = (src<<8)|(sub<<6)|dstlo.
//                 256-bin sort; gather + MFMA epilogue chunked 4x64 rows
//                 (agg planes time-share the raw staging union).
// Tier D fallback: atomic scatter + LDS linear (any size/ws).

#define DIM 64
#define BN 64             // nodes per bucket
#define BN_SHIFT 6
#define BN_MASK 63
#define NB_MAX 2048       // max buckets (prep hist LDS)
#define PB 256            // prep blocks
#define KMAX 8            // register-cached edges per thread
#define BPB 8192          // edges per prep-block region (= 1024*KMAX)
#define RAW4 5120         // super-bucket staging cap (mean 4096, +16 sigma)
#define AGS 64            // AGG LDS row stride in bf16
#define SBN 256           // nodes per super-bucket

typedef __attribute__((ext_vector_type(8))) short short8;
typedef __attribute__((ext_vector_type(4))) float f32x4;

__device__ __forceinline__ unsigned short f32_to_bf16_rne(float f) {
    unsigned u = __float_as_uint(f);
    unsigned r = u + 0x7FFFu + ((u >> 16) & 1u);
    return (unsigned short)(r >> 16);
}

// pack (a,b) -> bf16x2 hi word + bf16x2 lo (residual) word, RNE (bit-ops only).
__device__ __forceinline__ void pk2(float a, float b, unsigned &ph, unsigned &pl) {
    unsigned ha = f32_to_bf16_rne(a);
    unsigned hb = f32_to_bf16_rne(b);
    ph = ha | (hb << 16);
    float fa = __uint_as_float(ha << 16);
    float fb = __uint_as_float(hb << 16);
    unsigned la = f32_to_bf16_rne(a - fa);
    unsigned lb = f32_to_bf16_rne(b - fb);
    pl = la | (lb << 16);
}

__device__ __forceinline__ f32x4 mfma16(uint4 a, uint4 b, f32x4 c) {
    return __builtin_amdgcn_mfma_f32_16x16x32_bf16(
        __builtin_bit_cast(short8, a), __builtin_bit_cast(short8, b), c, 0, 0, 0);
}

// ---------------------------------------------------------------------------
// prep_sort: block-local counting sort + coalesced write-out. (r20, proven)
__global__ __launch_bounds__(1024) void prep_sort_kernel(
        const float* __restrict__ x, const int* __restrict__ ei,
        ushort4* __restrict__ xb4, int* __restrict__ binned,
        int* __restrict__ off, int E, int N, int nb, int total4) {
    __shared__ int h[NB_MAX];             // hist -> excl starts -> cursors
    __shared__ int staged[BPB];           // 32 KB block-sorted edges
    __shared__ int wsum[16];
    const int t = threadIdx.x;
    const int bid = blockIdx.x;
    const int lane = t & 63;
    const int wid = t >> 6;

    for (int b = t; b < nb; b += 1024) h[b] = 0;
    __syncthreads();

    // load edges ONCE into registers + LDS hist
    int es[KMAX], ds[KMAX];
    #pragma unroll
    for (int k = 0; k < KMAX; ++k) {
        int e = (k * PB + bid) * 1024 + t;      // coalesced per k
        if (e < E) {
            es[k] = ei[e];
            ds[k] = ei[E + e];
            atomicAdd(&h[ds[k] >> BN_SHIFT], 1);
        } else {
            ds[k] = -1;
        }
    }

    // convert x -> bf16 (+ zero row N) — independent, overlaps hist drain
    for (int i = bid * 1024 + t; i < total4; i += PB * 1024) {
        float4 v = ((const float4*)x)[i];
        ushort4 o;
        o.x = f32_to_bf16_rne(v.x); o.y = f32_to_bf16_rne(v.y);
        o.z = f32_to_bf16_rne(v.z); o.w = f32_to_bf16_rne(v.w);
        xb4[i] = o;
    }
    if (bid == 0 && t < 16) {
        ushort4 z; z.x = 0; z.y = 0; z.z = 0; z.w = 0;
        xb4[(size_t)N * 16 + t] = z;
    }
    __syncthreads();

    // block-wide exclusive scan over nb bins: thread owns bins 2t, 2t+1
    int c0 = (2 * t < nb) ? h[2 * t] : 0;
    int c1 = (2 * t + 1 < nb) ? h[2 * t + 1] : 0;
    int s = c0 + c1;
    int incl = s;
    #pragma unroll
    for (int d = 1; d < 64; d <<= 1) {
        int u = __shfl_up(incl, d, 64);
        if (lane >= d) incl += u;
    }
    if (lane == 63) wsum[wid] = incl;
    __syncthreads();                       // also fences the h[] reads above
    int woff = 0, EB = 0;
    for (int w = 0; w < 16; ++w) {
        if (w < wid) woff += wsum[w];
        EB += wsum[w];
    }
    int excl = woff + incl - s;
    if (2 * t < nb)     h[2 * t]     = excl;
    if (2 * t + 1 < nb) h[2 * t + 1] = excl + c0;
    __syncthreads();

    // write off table (column-major off[b][bid]) BEFORE cursors mutate
    for (int b = t; b <= nb; b += 1024) {
        int v = (b < nb) ? h[b] : EB;
        off[(size_t)b * PB + bid] = v;
    }
    __syncthreads();                       // h reads done before scatter

    // scatter into staged via LDS cursors
    #pragma unroll
    for (int k = 0; k < KMAX; ++k) {
        if (ds[k] >= 0) {
            int p = atomicAdd(&h[ds[k] >> BN_SHIFT], 1);
            staged[p] = (es[k] << BN_SHIFT) | (ds[k] & BN_MASK);
        }
    }
    __syncthreads();

    // coalesced copy-out to this block's own region
    for (int i = t; i < EB; i += 1024)
        binned[(size_t)bid * BPB + i] = staged[i];
}

// ---------------------------------------------------------------------------
// Gather helpers (proven r8-r18).
__device__ __forceinline__ void acc8(float (&a)[8], const uint4& v) {
    a[0] += __uint_as_float(v.x << 16); a[1] += __uint_as_float(v.x & 0xFFFF0000u);
    a[2] += __uint_as_float(v.y << 16); a[3] += __uint_as_float(v.y & 0xFFFF0000u);
    a[4] += __uint_as_float(v.z << 16); a[5] += __uint_as_float(v.z & 0xFFFF0000u);
    a[6] += __uint_as_float(v.w << 16); a[7] += __uint_as_float(v.w & 0xFFFF0000u);
}

// pack one agg row (8 f32 per lane) into hi/lo bf16 LDS planes.
#define PACK_STORE(AR, ROW)                                                   \
    do {                                                                      \
        unsigned ph0, ph1, ph2, ph3, pl0, pl1, pl2, pl3;                      \
        pk2(AR[0], AR[1], ph0, pl0); pk2(AR[2], AR[3], ph1, pl1);             \
        pk2(AR[4], AR[5], ph2, pl2); pk2(AR[6], AR[7], ph3, pl3);             \
        const int dco = (lane & 7) << 3;                                      \
        if (lane < 8) {                                                       \
            uint4 v; v.x = ph0; v.y = ph1; v.z = ph2; v.w = ph3;              \
            *(uint4*)&aggh[(ROW) * AGS + dco] = v;                            \
        } else if (lane < 16) {                                               \
            uint4 v; v.x = pl0; v.y = pl1; v.z = pl2; v.w = pl3;              \
            *(uint4*)&aggl[(ROW) * AGS + dco] = v;                            \
        }                                                                     \
    } while (0)

// ---------------------------------------------------------------------------
// sort_gather: super-bucket (4 buckets, 256 nodes, 512 thr).
__global__ __launch_bounds__(512) void sort_gather_kernel(
        const unsigned short* __restrict__ xh,
        const int* __restrict__ binned, const int* __restrict__ off,
        const float* __restrict__ W, const float* __restrict__ bias,
        float* __restrict__ out, int N, int nb) {
    __shared__ int cnt[SBN];
    __shared__ int basel[SBN + 1];
    __shared__ int wsum[8];
    __shared__ int sbase[PB], slen[PB], sgb[PB];
    __shared__ int sb1[PB], sb2[PB], sb3[PB];
    __shared__ int slds[RAW4];
    __shared__ __align__(16) int uni[RAW4];   // raw staging, then agg planes

    int* raw = uni;
    unsigned short* aggh = (unsigned short*)uni;            // 64*64*2B = 2048 ints
    unsigned short* aggl = (unsigned short*)(uni + 2048);   // next 2048 ints

    const int t = threadIdx.x;
    const int g = blockIdx.x;
    const int lane = t & 63;
    const int wid = t >> 6;
    const int node0 = g << 8;            // 256 nodes per super-bucket

    // ---- island meta (thread t<256 = prep block t), spans of 4 buckets ----
    if (t < PB) {
        int lo = min(4 * g,     nb);
        int r1 = min(4 * g + 1, nb);
        int r2 = min(4 * g + 2, nb);
        int r3 = min(4 * g + 3, nb);
        int hi = min(4 * g + 4, nb);
        int s_ = off[(size_t)lo * PB + t];
        int e_ = off[(size_t)hi * PB + t];
        slen[t] = e_ - s_;
        sgb[t]  = t * BPB + s_;
        sb1[t]  = off[(size_t)r1 * PB + t] - s_;
        sb2[t]  = off[(size_t)r2 * PB + t] - s_;
        sb3[t]  = off[(size_t)r3 * PB + t] - s_;
    }
    if (t < SBN) cnt[t] = 0;
    __syncthreads();

    // ---- scan island lengths -> staging bases (threads 0..255, 4 waves) ---
    int myl = (t < PB) ? slen[t] : 0;
    int v = myl;
    #pragma unroll
    for (int d = 1; d < 64; d <<= 1) {
        int u = __shfl_up(v, d, 64);
        if (lane >= d) v += u;
    }
    if (lane == 63 && wid < 4) wsum[wid] = v;
    __syncthreads();
    int total = wsum[0] + wsum[1] + wsum[2] + wsum[3];
    if (t < PB) {
        int w0 = 0;
        for (int w = 0; w < wid; ++w) w0 += wsum[w];
        sbase[t] = w0 + v - myl;
    }
    __syncthreads();
    const int tot = min(total, RAW4);

    // ---- stage spans into LDS: key = (src<<8)|(sub<<6)|dstlo --------------
    {
        const int tt = t & (PB - 1);
        const int half = t >> 8;             // 0 or 1
        const int ls = slen[tt];
        const int bs = sbase[tt];
        const int gbs = sgb[tt];
        const int B1 = sb1[tt], B2 = sb2[tt], B3 = sb3[tt];
        for (int j = half; j < ls; j += 2) {
            int w = binned[gbs + j];
            int sub = (j >= B3) ? 3 : ((j >= B2) ? 2 : ((j >= B1) ? 1 : 0));
            int p = bs + j;
            if (p < RAW4)
                raw[p] = ((w >> BN_SHIFT) << 8) | (sub << 6) | (w & BN_MASK);
        }
    }
    __syncthreads();

    // ---- hist over 256 node bins ------------------------------------------
    for (int i = t; i < tot; i += 512)
        atomicAdd(&cnt[raw[i] & 255], 1);
    __syncthreads();

    // ---- 256-bin exclusive scan (threads 0..255) --------------------------
    int myv = (t < SBN) ? cnt[t] : 0;
    int iv = myv;
    #pragma unroll
    for (int d = 1; d < 64; d <<= 1) {
        int u = __shfl_up(iv, d, 64);
        if (lane >= d) iv += u;
    }
    if (lane == 63 && wid < 4) wsum[wid] = iv;
    __syncthreads();
    if (t < SBN) {
        int w0 = 0;
        for (int w = 0; w < wid; ++w) w0 += wsum[w];
        int excl = w0 + iv - myv;
        basel[t] = excl;
        cnt[t] = excl;                       // cursors
    }
    if (t == 0) basel[SBN] = tot;
    __syncthreads();

    // ---- counting-sort scatter into slds (src only) -----------------------
    for (int i = t; i < tot; i += 512) {
        int w = raw[i];
        int p = atomicAdd(&cnt[w & 255], 1);
        slds[p] = w >> 8;
    }
    __syncthreads();   // raw (uni) dead from here

    // ---- gather + epilogue, 4 chunks of 64 nodes --------------------------
    const int sub8 = lane >> 3;
    const int fb   = (lane & 7) << 3;
    const int zrow = N;
    const int l15 = lane & 15;
    const int kq  = lane >> 4;

    for (int ch = 0; ch < 4; ++ch) {
        const int nbase = ch << 6;

        for (int q = wid; q < 16; q += 8) {
            const int nl = nbase + (q << 2);
            int b0 = basel[nl + 0], e0 = basel[nl + 1];
            int b1 = basel[nl + 1], e1 = basel[nl + 2];
            int b2 = basel[nl + 2], e2 = basel[nl + 3];
            int b3 = basel[nl + 3], e3 = basel[nl + 4];
            int c0 = (e0 - b0 + 7) >> 3, c1 = (e1 - b1 + 7) >> 3;
            int c2 = (e2 - b2 + 7) >> 3, c3 = (e3 - b3 + 7) >> 3;
            int cmax = max(max(c0, c1), max(c2, c3));
            cmax = __builtin_amdgcn_readfirstlane(cmax);

            float A0[8] = {0.f,0.f,0.f,0.f,0.f,0.f,0.f,0.f};
            float A1[8] = {0.f,0.f,0.f,0.f,0.f,0.f,0.f,0.f};
            float A2[8] = {0.f,0.f,0.f,0.f,0.f,0.f,0.f,0.f};
            float A3[8] = {0.f,0.f,0.f,0.f,0.f,0.f,0.f,0.f};

            for (int c = 0; c < cmax; ++c) {
                const int o = (c << 3) + sub8;
                int i0 = b0 + o, i1 = b1 + o, i2 = b2 + o, i3 = b3 + o;
                int s0 = slds[min(i0, RAW4 - 1)];
                int s1 = slds[min(i1, RAW4 - 1)];
                int s2 = slds[min(i2, RAW4 - 1)];
                int s3 = slds[min(i3, RAW4 - 1)];
                s0 = (i0 < e0) ? s0 : zrow;
                s1 = (i1 < e1) ? s1 : zrow;
                s2 = (i2 < e2) ? s2 : zrow;
                s3 = (i3 < e3) ? s3 : zrow;
                uint4 v0 = *(const uint4*)(xh + (size_t)s0 * DIM + fb);
                uint4 v1 = *(const uint4*)(xh + (size_t)s1 * DIM + fb);
                uint4 v2 = *(const uint4*)(xh + (size_t)s2 * DIM + fb);
                uint4 v3 = *(const uint4*)(xh + (size_t)s3 * DIM + fb);
                acc8(A0, v0); acc8(A1, v1); acc8(A2, v2); acc8(A3, v3);
            }

            #pragma unroll
            for (int d = 8; d <= 32; d <<= 1) {
                #pragma unroll
                for (int j = 0; j < 8; ++j) {
                    A0[j] += __shfl_xor(A0[j], d, 64);
                    A1[j] += __shfl_xor(A1[j], d, 64);
                    A2[j] += __shfl_xor(A2[j], d, 64);
                    A3[j] += __shfl_xor(A3[j], d, 64);
                }
            }

            PACK_STORE(A0, (q << 2) + 0);
            PACK_STORE(A1, (q << 2) + 1);
            PACK_STORE(A2, (q << 2) + 2);
            PACK_STORE(A3, (q << 2) + 3);
        }

        __syncthreads();   // chunk's 64 agg rows written

        // MFMA epilogue for this chunk (waves 0-3, 16 rows each)
        if (wid < 4) {
            const int mbase = wid << 4;

            const unsigned short* arow_h = aggh + (mbase + l15) * AGS + (kq << 3);
            const unsigned short* arow_l = aggl + (mbase + l15) * AGS + (kq << 3);
            uint4 ah0 = *(const uint4*)(arow_h);
            uint4 ah1 = *(const uint4*)(arow_h + 32);
            uint4 al0 = *(const uint4*)(arow_l);
            uint4 al1 = *(const uint4*)(arow_l + 32);

            f32x4 acc[4];
            #pragma unroll
            for (int n = 0; n < 4; ++n) {
                float bb = bias[(n << 4) + l15];
                acc[n] = (f32x4){bb, bb, bb, bb};
            }

            #pragma unroll
            for (int n = 0; n < 4; ++n) {
                const float* wr = W + (size_t)((n << 4) + l15) * DIM + (kq << 3);
                float4 wa = *(const float4*)(wr);
                float4 wb = *(const float4*)(wr + 4);
                float4 wc = *(const float4*)(wr + 32);
                float4 wd = *(const float4*)(wr + 36);
                uint4 bh0, bl0, bh1, bl1;
                pk2(wa.x, wa.y, bh0.x, bl0.x); pk2(wa.z, wa.w, bh0.y, bl0.y);
                pk2(wb.x, wb.y, bh0.z, bl0.z); pk2(wb.z, wb.w, bh0.w, bl0.w);
                pk2(wc.x, wc.y, bh1.x, bl1.x); pk2(wc.z, wc.w, bh1.y, bl1.y);
                pk2(wd.x, wd.y, bh1.z, bl1.z); pk2(wd.z, wd.w, bh1.w, bl1.w);
                acc[n] = mfma16(ah0, bh0, acc[n]);
                acc[n] = mfma16(al0, bh0, acc[n]);
                acc[n] = mfma16(ah0, bl0, acc[n]);
                acc[n] = mfma16(ah1, bh1, acc[n]);
                acc[n] = mfma16(al1, bh1, acc[n]);
                acc[n] = mfma16(ah1, bl1, acc[n]);
            }

            // C/D layout: col = lane&15, row = (lane>>4)*4 + i  [m89]
            #pragma unroll
            for (int n = 0; n < 4; ++n) {
                #pragma unroll
                for (int i = 0; i < 4; ++i) {
                    int node = node0 + nbase + mbase + (kq << 2) + i;
                    if (node < N)
                        out[(size_t)node * DIM + (n << 4) + l15] = acc[n][i];
                }
            }
        }
        __syncthreads();   // agg free for next chunk
    }
}

// ------------------- tier D: atomic scatter fallback -----------------------
__global__ void gcn_scatter_kernel(const float* __restrict__ x,
                                   const int* __restrict__ edge_index,
                                   float* __restrict__ out, int n_edges) {
    int gid = blockIdx.x * blockDim.x + threadIdx.x;
    int e = gid >> 4;
    if (e >= n_edges) return;
    int j = (gid & 15) << 2;
    int src = edge_index[e];
    int dst = edge_index[n_edges + e];
    const float4 v = *(const float4*)(x + (size_t)src * DIM + j);
    float* o = out + (size_t)dst * DIM + j;
    atomicAdd(o + 0, v.x); atomicAdd(o + 1, v.y);
    atomicAdd(o + 2, v.z); atomicAdd(o + 3, v.w);
}

__global__ void gcn_linear_inplace_kernel(float* __restrict__ out,
                                          const float* __restrict__ W,
                                          const float* __restrict__ bias,
                                          int n_nodes) {
    __shared__ float Wt[DIM * DIM];
    __shared__ float rows[4][DIM];
    int tid = threadIdx.x;
    int col = tid & 63;
    int r = tid >> 6;
    for (int i = tid; i < DIM * DIM; i += 256) {
        int c = i >> 6, k = i & 63;
        Wt[k * DIM + c] = W[i];
    }
    int row = blockIdx.x * 4 + r;
    if (row < n_nodes) rows[r][col] = out[(size_t)row * DIM + col];
    __syncthreads();
    if (row < n_nodes) {
        float a = 0.f;
        #pragma unroll
        for (int k = 0; k < DIM; ++k) a += rows[r][k] * Wt[k * DIM + col];
        out[(size_t)row * DIM + col] = a + bias[col];
    }
}

// ===========================================================================
extern "C" void kernel_launch(void* const* d_in, const int* in_sizes, int n_in,
                              void* d_out, int out_size, void* d_ws, size_t ws_size,
                              hipStream_t stream) {
    const float* x          = (const float*)d_in[0];   // [N, 64]
    const float* W          = (const float*)d_in[1];   // [64, 64]
    const float* bias       = (const float*)d_in[2];   // [64]
    const int*   edge_index = (const int*)d_in[3];     // [2, E] (int32)

    const int E = in_sizes[3] / 2;
    const int N = in_sizes[0] / DIM;
    float* out = (float*)d_out;

    const int nb  = (N + BN - 1) >> BN_SHIFT;
    const int nbg = (nb + 3) >> 2;          // super-buckets

    auto align256 = [](size_t v) { return (v + 255) & ~(size_t)255; };
    const size_t xb_b  = align256(((size_t)N + 1) * DIM * 2);   // +1 zero row
    const size_t bin_b = align256((size_t)PB * BPB * 4);        // 8 MB
    const size_t off_b = align256(((size_t)nb + 1) * PB * 4);
    const size_t need  = xb_b + bin_b + off_b;

    // src must fit in 24 bits for the (src<<8)|sub|dstlo packing
    if (nb < NB_MAX && N < (1 << 24) && ws_size >= need &&
        (long long)E <= (long long)PB * 1024 * KMAX) {
        char* p = (char*)d_ws;
        ushort4* xb4 = (ushort4*)p;          p += xb_b;
        int* binned  = (int*)p;              p += bin_b;
        int* off     = (int*)p;

        const int total4 = N * DIM / 4;

        prep_sort_kernel<<<PB, 1024, 0, stream>>>(
            x, edge_index, xb4, binned, off, E, N, nb, total4);
        sort_gather_kernel<<<nbg, 512, 0, stream>>>(
            (const unsigned short*)xb4, binned, off, W, bias, out, N, nb);
    } else {
        hipMemsetAsync(d_out, 0, (size_t)out_size * sizeof(float), stream);
        long long total = (long long)E * 16;
        int grid = (int)((total + 255) / 256);
        gcn_scatter_kernel<<<grid, 256, 0, stream>>>(x, edge_index, out, E);
        int lgrid = (N + 3) / 4;
        gcn_linear_inplace_kernel<<<lgrid, 256, 0, stream>>>(out, W, bias, N);
    }
}

// Round 10
// 172.323 us; speedup vs baseline: 1.0573x; 1.0573x over previous
//
#include <hip/hip_runtime.h>

// GCN layer: segment_sum(x@W^T)[dst] == segment_sum(x)[dst] @ W^T (linearity).
// Round-23: 2 dispatches.
//   prep_sort   : (r20, kept) block-local LDS counting sort; coalesced
//                 binned write; column-major off table.
//   sort_gather : r21 structure (64-node bucket, single-pass island staging,
//                 raw/agg LDS union) at 512 THREADS, UNPINNED launch_bounds.
//                 Clean TLP test: r17's pin forced VGPR 52->32 (spills);
//                 unpinned the body fits <=64 VGPR -> 4 blocks x 8 waves =
//                 32 waves/CU vs r21's 24 (LDS-capped 6x4). +33% latency
//                 hiding on the latency-bound gather, no traffic change.
// Tier D fallback: atomic scatter + LDS linear (any size/ws).

#define DIM 64
#define BN 64             // nodes per bucket
#define BN_SHIFT 6
#define BN_MASK 63
#define NB_MAX 2048       // max buckets (prep hist LDS)
#define PB 256            // prep blocks
#define KMAX 8            // register-cached edges per thread
#define BPB 8192          // edges per prep-block region (= 1024*KMAX)
#define SLDS_CAP 1536     // bucket edge capacity (mean 1024, +16 sigma)
#define RAWCAP 2048       // staging cap (aggh plane = 8KB = 2048 ints)
#define AGS 64            // AGG LDS row stride in bf16
#define SGT 512           // sort_gather threads

typedef __attribute__((ext_vector_type(8))) short short8;
typedef __attribute__((ext_vector_type(4))) float f32x4;

__device__ __forceinline__ unsigned short f32_to_bf16_rne(float f) {
    unsigned u = __float_as_uint(f);
    unsigned r = u + 0x7FFFu + ((u >> 16) & 1u);
    return (unsigned short)(r >> 16);
}

// pack (a,b) -> bf16x2 hi word + bf16x2 lo (residual) word, RNE (bit-ops only).
__device__ __forceinline__ void pk2(float a, float b, unsigned &ph, unsigned &pl) {
    unsigned ha = f32_to_bf16_rne(a);
    unsigned hb = f32_to_bf16_rne(b);
    ph = ha | (hb << 16);
    float fa = __uint_as_float(ha << 16);
    float fb = __uint_as_float(hb << 16);
    unsigned la = f32_to_bf16_rne(a - fa);
    unsigned lb = f32_to_bf16_rne(b - fb);
    pl = la | (lb << 16);
}

__device__ __forceinline__ f32x4 mfma16(uint4 a, uint4 b, f32x4 c) {
    return __builtin_amdgcn_mfma_f32_16x16x32_bf16(
        __builtin_bit_cast(short8, a), __builtin_bit_cast(short8, b), c, 0, 0, 0);
}

// ---------------------------------------------------------------------------
// prep_sort: block-local counting sort + coalesced write-out. (r20, proven)
__global__ __launch_bounds__(1024) void prep_sort_kernel(
        const float* __restrict__ x, const int* __restrict__ ei,
        ushort4* __restrict__ xb4, int* __restrict__ binned,
        int* __restrict__ off, int E, int N, int nb, int total4) {
    __shared__ int h[NB_MAX];             // hist -> excl starts -> cursors
    __shared__ int staged[BPB];           // 32 KB block-sorted edges
    __shared__ int wsum[16];
    const int t = threadIdx.x;
    const int bid = blockIdx.x;
    const int lane = t & 63;
    const int wid = t >> 6;

    for (int b = t; b < nb; b += 1024) h[b] = 0;
    __syncthreads();

    // load edges ONCE into registers + LDS hist
    int es[KMAX], ds[KMAX];
    #pragma unroll
    for (int k = 0; k < KMAX; ++k) {
        int e = (k * PB + bid) * 1024 + t;      // coalesced per k
        if (e < E) {
            es[k] = ei[e];
            ds[k] = ei[E + e];
            atomicAdd(&h[ds[k] >> BN_SHIFT], 1);
        } else {
            ds[k] = -1;
        }
    }

    // convert x -> bf16 (+ zero row N) — independent, overlaps hist drain
    for (int i = bid * 1024 + t; i < total4; i += PB * 1024) {
        float4 v = ((const float4*)x)[i];
        ushort4 o;
        o.x = f32_to_bf16_rne(v.x); o.y = f32_to_bf16_rne(v.y);
        o.z = f32_to_bf16_rne(v.z); o.w = f32_to_bf16_rne(v.w);
        xb4[i] = o;
    }
    if (bid == 0 && t < 16) {
        ushort4 z; z.x = 0; z.y = 0; z.z = 0; z.w = 0;
        xb4[(size_t)N * 16 + t] = z;
    }
    __syncthreads();

    // block-wide exclusive scan over nb bins: thread owns bins 2t, 2t+1
    int c0 = (2 * t < nb) ? h[2 * t] : 0;
    int c1 = (2 * t + 1 < nb) ? h[2 * t + 1] : 0;
    int s = c0 + c1;
    int incl = s;
    #pragma unroll
    for (int d = 1; d < 64; d <<= 1) {
        int u = __shfl_up(incl, d, 64);
        if (lane >= d) incl += u;
    }
    if (lane == 63) wsum[wid] = incl;
    __syncthreads();                       // also fences the h[] reads above
    int woff = 0, EB = 0;
    for (int w = 0; w < 16; ++w) {
        if (w < wid) woff += wsum[w];
        EB += wsum[w];
    }
    int excl = woff + incl - s;
    if (2 * t < nb)     h[2 * t]     = excl;
    if (2 * t + 1 < nb) h[2 * t + 1] = excl + c0;
    __syncthreads();

    // write off table (column-major off[b][bid]) BEFORE cursors mutate
    for (int b = t; b <= nb; b += 1024) {
        int v = (b < nb) ? h[b] : EB;
        off[(size_t)b * PB + bid] = v;
    }
    __syncthreads();                       // h reads done before scatter

    // scatter into staged via LDS cursors
    #pragma unroll
    for (int k = 0; k < KMAX; ++k) {
        if (ds[k] >= 0) {
            int p = atomicAdd(&h[ds[k] >> BN_SHIFT], 1);
            staged[p] = (es[k] << BN_SHIFT) | (ds[k] & BN_MASK);
        }
    }
    __syncthreads();

    // coalesced copy-out to this block's own region
    for (int i = t; i < EB; i += 1024)
        binned[(size_t)bid * BPB + i] = staged[i];
}

// ---------------------------------------------------------------------------
// Gather helpers (proven r8-r18).
__device__ __forceinline__ void acc8(float (&a)[8], const uint4& v) {
    a[0] += __uint_as_float(v.x << 16); a[1] += __uint_as_float(v.x & 0xFFFF0000u);
    a[2] += __uint_as_float(v.y << 16); a[3] += __uint_as_float(v.y & 0xFFFF0000u);
    a[4] += __uint_as_float(v.z << 16); a[5] += __uint_as_float(v.z & 0xFFFF0000u);
    a[6] += __uint_as_float(v.w << 16); a[7] += __uint_as_float(v.w & 0xFFFF0000u);
}

// pack one agg row (8 f32 per lane) into hi/lo bf16 LDS planes.
#define PACK_STORE(AR, ROW)                                                   \
    do {                                                                      \
        unsigned ph0, ph1, ph2, ph3, pl0, pl1, pl2, pl3;                      \
        pk2(AR[0], AR[1], ph0, pl0); pk2(AR[2], AR[3], ph1, pl1);             \
        pk2(AR[4], AR[5], ph2, pl2); pk2(AR[6], AR[7], ph3, pl3);             \
        const int dco = (lane & 7) << 3;                                      \
        if (lane < 8) {                                                       \
            uint4 v; v.x = ph0; v.y = ph1; v.z = ph2; v.w = ph3;              \
            *(uint4*)&aggh[(ROW) * AGS + dco] = v;                            \
        } else if (lane < 16) {                                               \
            uint4 v; v.x = pl0; v.y = pl1; v.z = pl2; v.w = pl3;              \
            *(uint4*)&aggl[(ROW) * AGS + dco] = v;                            \
        }                                                                     \
    } while (0)

// ---------------------------------------------------------------------------
// sort_gather: 512 thr, single-pass island staging -> in-LDS sort -> gather.
__global__ __launch_bounds__(SGT) void sort_gather_kernel(
        const unsigned short* __restrict__ xh,
        const int* __restrict__ binned, const int* __restrict__ off,
        const float* __restrict__ W, const float* __restrict__ bias,
        float* __restrict__ out, int N) {
    __shared__ int cnt[BN];
    __shared__ int basel[BN + 1];
    __shared__ int wsum[8];
    __shared__ int slen[PB], sgb[PB], sbase[PB];
    __shared__ int slds[SLDS_CAP];
    __shared__ __align__(16) unsigned short aggh[BN * AGS];  // raw staging first
    __shared__ __align__(16) unsigned short aggl[BN * AGS];

    int* raw = (int*)aggh;                // time-shared: staging dies pre-epilogue

    const int t = threadIdx.x;
    const int g = blockIdx.x;
    const int lane = t & 63;
    const int wid = t >> 6;
    const int node0 = g << BN_SHIFT;

    // island meta (threads 0..255 = prep blocks)
    int l_ = 0;
    if (t < PB) {
        int s_ = off[(size_t)g * PB + t];         // coalesced
        int e_ = off[(size_t)(g + 1) * PB + t];   // coalesced
        l_ = e_ - s_;
        slen[t] = l_;
        sgb[t]  = t * BPB + s_;
    }
    if (t < BN) cnt[t] = 0;

    // scan island lengths -> staging base (waves 0-3 carry data)
    int incl = l_;
    #pragma unroll
    for (int d = 1; d < 64; d <<= 1) {
        int u = __shfl_up(incl, d, 64);
        if (lane >= d) incl += u;
    }
    if (lane == 63) wsum[wid] = incl;
    __syncthreads();
    int total = wsum[0] + wsum[1] + wsum[2] + wsum[3];
    if (t < PB) {
        int w0 = 0;
        #pragma unroll
        for (int w = 0; w < 4; ++w) if (w < wid) w0 += wsum[w];
        sbase[t] = w0 + incl - l_;
    }
    __syncthreads();
    const int tot = min(total, RAWCAP);

    // stage islands into LDS (ONE global pass; island t split over 2 threads)
    {
        const int tt = t & (PB - 1);
        const int half = t >> 8;             // 0 or 1
        const int ls = slen[tt];
        const int bs = sbase[tt];
        const int gbs = sgb[tt];
        for (int j = half; j < ls; j += 2) {
            int p = bs + j;
            if (p < RAWCAP) raw[p] = binned[gbs + j];
        }
    }
    __syncthreads();

    // hist from LDS
    for (int i = t; i < tot; i += SGT)
        atomicAdd(&cnt[raw[i] & BN_MASK], 1);
    __syncthreads();

    // single-wave inclusive shfl scan over the 64 bins (wave 0 only)
    if (t < BN) {
        int myv = cnt[t];
        int v = myv;
        #pragma unroll
        for (int d = 1; d < BN; d <<= 1) {
            int u = __shfl_up(v, d, 64);
            if (t >= d) v += u;
        }
        basel[t] = v - myv;
        if (t == BN - 1) basel[BN] = v;
        cnt[t] = v - myv;                     // cursors
    }
    __syncthreads();

    // in-LDS counting-sort scatter
    for (int i = t; i < tot; i += SGT) {
        int v = raw[i];
        int p = atomicAdd(&cnt[v & BN_MASK], 1);
        if (p < SLDS_CAP) slds[p] = v >> BN_SHIFT;
    }
    __syncthreads();   // raw (aggh) dead from here

    const int sub8 = lane >> 3;
    const int fb   = (lane & 7) << 3;
    const int zrow = N;
    for (int q = wid; q < (BN >> 2); q += 8) {
        const int nl = q << 2;
        int b0 = basel[nl + 0], e0 = basel[nl + 1];
        int b1 = basel[nl + 1], e1 = basel[nl + 2];
        int b2 = basel[nl + 2], e2 = basel[nl + 3];
        int b3 = basel[nl + 3], e3 = basel[nl + 4];
        int c0 = (e0 - b0 + 7) >> 3, c1 = (e1 - b1 + 7) >> 3;
        int c2 = (e2 - b2 + 7) >> 3, c3 = (e3 - b3 + 7) >> 3;
        int cmax = max(max(c0, c1), max(c2, c3));
        cmax = __builtin_amdgcn_readfirstlane(cmax);

        float A0[8] = {0.f,0.f,0.f,0.f,0.f,0.f,0.f,0.f};
        float A1[8] = {0.f,0.f,0.f,0.f,0.f,0.f,0.f,0.f};
        float A2[8] = {0.f,0.f,0.f,0.f,0.f,0.f,0.f,0.f};
        float A3[8] = {0.f,0.f,0.f,0.f,0.f,0.f,0.f,0.f};

        for (int c = 0; c < cmax; ++c) {
            const int o = (c << 3) + sub8;
            int i0 = b0 + o, i1 = b1 + o, i2 = b2 + o, i3 = b3 + o;
            int s0 = slds[min(i0, SLDS_CAP - 1)];
            int s1 = slds[min(i1, SLDS_CAP - 1)];
            int s2 = slds[min(i2, SLDS_CAP - 1)];
            int s3 = slds[min(i3, SLDS_CAP - 1)];
            s0 = (i0 < e0) ? s0 : zrow;
            s1 = (i1 < e1) ? s1 : zrow;
            s2 = (i2 < e2) ? s2 : zrow;
            s3 = (i3 < e3) ? s3 : zrow;
            uint4 v0 = *(const uint4*)(xh + (size_t)s0 * DIM + fb);
            uint4 v1 = *(const uint4*)(xh + (size_t)s1 * DIM + fb);
            uint4 v2 = *(const uint4*)(xh + (size_t)s2 * DIM + fb);
            uint4 v3 = *(const uint4*)(xh + (size_t)s3 * DIM + fb);
            acc8(A0, v0); acc8(A1, v1); acc8(A2, v2); acc8(A3, v3);
        }

        #pragma unroll
        for (int d = 8; d <= 32; d <<= 1) {
            #pragma unroll
            for (int j = 0; j < 8; ++j) {
                A0[j] += __shfl_xor(A0[j], d, 64);
                A1[j] += __shfl_xor(A1[j], d, 64);
                A2[j] += __shfl_xor(A2[j], d, 64);
                A3[j] += __shfl_xor(A3[j], d, 64);
            }
        }

        // pack AGG rows into hi/lo bf16 LDS planes (exact to ~16 mantissa bits)
        PACK_STORE(A0, nl + 0);
        PACK_STORE(A1, nl + 1);
        PACK_STORE(A2, nl + 2);
        PACK_STORE(A3, nl + 3);
    }

    __syncthreads();   // all AGG rows written

    // ---- MFMA epilogue: out[64x64] = AGG @ W^T + bias, waves 0-3 ----------
    if (wid < 4) {
        const int mbase = wid << 4;          // wave's 16 node rows
        const int l15 = lane & 15;
        const int kq  = lane >> 4;           // k-chunk 0..3

        const unsigned short* arow_h = aggh + (mbase + l15) * AGS + (kq << 3);
        const unsigned short* arow_l = aggl + (mbase + l15) * AGS + (kq << 3);
        uint4 ah0 = *(const uint4*)(arow_h);
        uint4 ah1 = *(const uint4*)(arow_h + 32);
        uint4 al0 = *(const uint4*)(arow_l);
        uint4 al1 = *(const uint4*)(arow_l + 32);

        f32x4 acc[4];
        #pragma unroll
        for (int n = 0; n < 4; ++n) {
            float bb = bias[(n << 4) + l15];
            acc[n] = (f32x4){bb, bb, bb, bb};
        }

        #pragma unroll
        for (int n = 0; n < 4; ++n) {
            const float* wr = W + (size_t)((n << 4) + l15) * DIM + (kq << 3);
            float4 wa = *(const float4*)(wr);
            float4 wb = *(const float4*)(wr + 4);
            float4 wc = *(const float4*)(wr + 32);
            float4 wd = *(const float4*)(wr + 36);
            uint4 bh0, bl0, bh1, bl1;
            pk2(wa.x, wa.y, bh0.x, bl0.x); pk2(wa.z, wa.w, bh0.y, bl0.y);
            pk2(wb.x, wb.y, bh0.z, bl0.z); pk2(wb.z, wb.w, bh0.w, bl0.w);
            pk2(wc.x, wc.y, bh1.x, bl1.x); pk2(wc.z, wc.w, bh1.y, bl1.y);
            pk2(wd.x, wd.y, bh1.z, bl1.z); pk2(wd.z, wd.w, bh1.w, bl1.w);
            // (Ah+Al)(Wh+Wl) ~= AhWh + AlWh + AhWl  (AlWl ~ 2^-18, dropped)
            acc[n] = mfma16(ah0, bh0, acc[n]);
            acc[n] = mfma16(al0, bh0, acc[n]);
            acc[n] = mfma16(ah0, bl0, acc[n]);
            acc[n] = mfma16(ah1, bh1, acc[n]);
            acc[n] = mfma16(al1, bh1, acc[n]);
            acc[n] = mfma16(ah1, bl1, acc[n]);
        }

        // C/D layout: col = lane&15, row = (lane>>4)*4 + i   [m89-verified]
        #pragma unroll
        for (int n = 0; n < 4; ++n) {
            #pragma unroll
            for (int i = 0; i < 4; ++i) {
                int node = node0 + mbase + (kq << 2) + i;
                if (node < N)
                    out[(size_t)node * DIM + (n << 4) + l15] = acc[n][i];
            }
        }
    }
}

// ------------------- tier D: atomic scatter fallback -----------------------
__global__ void gcn_scatter_kernel(const float* __restrict__ x,
                                   const int* __restrict__ edge_index,
                                   float* __restrict__ out, int n_edges) {
    int gid = blockIdx.x * blockDim.x + threadIdx.x;
    int e = gid >> 4;
    if (e >= n_edges) return;
    int j = (gid & 15) << 2;
    int src = edge_index[e];
    int dst = edge_index[n_edges + e];
    const float4 v = *(const float4*)(x + (size_t)src * DIM + j);
    float* o = out + (size_t)dst * DIM + j;
    atomicAdd(o + 0, v.x); atomicAdd(o + 1, v.y);
    atomicAdd(o + 2, v.z); atomicAdd(o + 3, v.w);
}

__global__ void gcn_linear_inplace_kernel(float* __restrict__ out,
                                          const float* __restrict__ W,
                                          const float* __restrict__ bias,
                                          int n_nodes) {
    __shared__ float Wt[DIM * DIM];
    __shared__ float rows[4][DIM];
    int tid = threadIdx.x;
    int col = tid & 63;
    int r = tid >> 6;
    for (int i = tid; i < DIM * DIM; i += 256) {
        int c = i >> 6, k = i & 63;
        Wt[k * DIM + c] = W[i];
    }
    int row = blockIdx.x * 4 + r;
    if (row < n_nodes) rows[r][col] = out[(size_t)row * DIM + col];
    __syncthreads();
    if (row < n_nodes) {
        float a = 0.f;
        #pragma unroll
        for (int k = 0; k < DIM; ++k) a += rows[r][k] * Wt[k * DIM + col];
        out[(size_t)row * DIM + col] = a + bias[col];
    }
}

// ===========================================================================
extern "C" void kernel_launch(void* const* d_in, const int* in_sizes, int n_in,
                              void* d_out, int out_size, void* d_ws, size_t ws_size,
                              hipStream_t stream) {
    const float* x          = (const float*)d_in[0];   // [N, 64]
    const float* W          = (const float*)d_in[1];   // [64, 64]
    const float* bias       = (const float*)d_in[2];   // [64]
    const int*   edge_index = (const int*)d_in[3];     // [2, E] (int32)

    const int E = in_sizes[3] / 2;
    const int N = in_sizes[0] / DIM;
    float* out = (float*)d_out;

    const int nb = (N + BN - 1) >> BN_SHIFT;

    auto align256 = [](size_t v) { return (v + 255) & ~(size_t)255; };
    const size_t xb_b  = align256(((size_t)N + 1) * DIM * 2);   // +1 zero row
    const size_t bin_b = align256((size_t)PB * BPB * 4);        // 8 MB
    const size_t off_b = align256(((size_t)nb + 1) * PB * 4);
    const size_t need  = xb_b + bin_b + off_b;

    // src must fit in 26 bits for the (src<<6)|dstlo packing
    if (nb < NB_MAX && N < (1 << 24) && ws_size >= need &&
        (long long)E <= (long long)PB * 1024 * KMAX) {
        char* p = (char*)d_ws;
        ushort4* xb4 = (ushort4*)p;          p += xb_b;
        int* binned  = (int*)p;              p += bin_b;
        int* off     = (int*)p;

        const int total4 = N * DIM / 4;

        prep_sort_kernel<<<PB, 1024, 0, stream>>>(
            x, edge_index, xb4, binned, off, E, N, nb, total4);
        sort_gather_kernel<<<nb, SGT, 0, stream>>>(
            (const unsigned short*)xb4, binned, off, W, bias, out, N);
    } else {
        hipMemsetAsync(d_out, 0, (size_t)out_size * sizeof(float), stream);
        long long total = (long long)E * 16;
        int grid = (int)((total + 255) / 256);
        gcn_scatter_kernel<<<grid, 256, 0, stream>>>(x, edge_index, out, E);
        int lgrid = (N + 3) / 4;
        gcn_linear_inplace_kernel<<<lgrid, 256, 0, stream>>>(out, W, bias, N);
    }
}